// Round 2
// baseline (3042.601 us; speedup 1.0000x reference)
//
#include <hip/hip_runtime.h>
#include <hip/hip_bf16.h>

#define Bv 32
#define Tv 512
#define Iv 512
#define Hv 1024
#define NG 4096  // 4*H

typedef short bf16x8 __attribute__((ext_vector_type(8)));   // 8 bf16 held as i16 (guide §3)
typedef float floatx16 __attribute__((ext_vector_type(16)));
typedef unsigned short u16;
typedef unsigned long long u64;

__device__ __forceinline__ u16 f2bf(float f) {
  __hip_bfloat16 h = __float2bfloat16(f);
  return *reinterpret_cast<u16*>(&h);
}

__device__ __forceinline__ floatx16 mfma32(bf16x8 a, bf16x8 b, floatx16 c) {
  return __builtin_amdgcn_mfma_f32_32x32x16_bf16(a, b, c, 0, 0, 0);
}

// relaxed agent-scope accesses: lower to global_load/store with sc1 (LLC-direct,
// bypass non-coherent per-XCD L2). No cache-maintenance instructions emitted.
__device__ __forceinline__ u64 ld_agent_u64(const u64* p) {
  return __hip_atomic_load(p, __ATOMIC_RELAXED, __HIP_MEMORY_SCOPE_AGENT);
}
__device__ __forceinline__ void st_agent_u16(u16* p, u16 v) {
  __hip_atomic_store(p, v, __ATOMIC_RELAXED, __HIP_MEMORY_SCOPE_AGENT);
}

__device__ __forceinline__ bf16x8 mk_frag(u64 lo, u64 hi) {
  union { u64 q[2]; bf16x8 v; } u;
  u.q[0] = lo; u.q[1] = hi;
  return u.v;
}

// ---------------- init: zero flag region (4KB) + hA double buffer (128KB)
__global__ void k_init(unsigned int* p, int n) {
  int i = blockIdx.x * blockDim.x + threadIdx.x;
  if (i < n) p[i] = 0u;
}

// ---------------- elementwise fp32 -> bf16
__global__ void k_f2bf(const float* __restrict__ in, u16* __restrict__ out, int n) {
  int i = blockIdx.x * blockDim.x + threadIdx.x;
  if (i < n) out[i] = f2bf(in[i]);
}

// ---------------- gather Wh into B-fragment layout: WhF[bl(64)][nt(2)][kt(64)][lane(64)][8]
__global__ void k_whf(const float* __restrict__ Wh, u16* __restrict__ whf) {
  int tid = blockIdx.x * 256 + threadIdx.x;   // 2048*256 = 524288
  int lane = tid & 63;
  int kt   = (tid >> 6) & 63;
  int nt   = (tid >> 12) & 1;
  int bl   = tid >> 13;
  int r    = nt * 32 + (lane & 31);
  int gate = r >> 4, du = r & 15;
  int row  = gate * Hv + bl * 16 + du;
  int k0   = kt * 16 + (lane >> 5) * 8;
  const float* s = Wh + (size_t)row * Hv + k0;
  u16* d = whf + (size_t)tid * 8;
#pragma unroll
  for (int j = 0; j < 8; ++j) d[j] = f2bf(s[j]);
}

// ---------------- xg GEMM (unchanged)
__global__ __launch_bounds__(256) void k_xg(const u16* __restrict__ xb, const u16* __restrict__ wxb,
                                            const float* __restrict__ bx, const float* __restrict__ bh,
                                            float* __restrict__ xg, int t0, int tcshift) {
  __shared__ u16 Al[128 * 40];
  __shared__ u16 Bl[128 * 40];
  int tid = threadIdx.x;
  int wave = tid >> 6, lane = tid & 63;
  int wm = wave & 1, wn = wave >> 1;
  int bm = blockIdx.x, bn = blockIdx.y;
  int Tc = 1 << tcshift;

  floatx16 acc[2][2];
#pragma unroll
  for (int a = 0; a < 2; ++a)
#pragma unroll
    for (int c = 0; c < 2; ++c)
#pragma unroll
      for (int r = 0; r < 16; ++r) acc[a][c][r] = 0.f;

  int lr = tid >> 1;
  int lk = (tid & 1) * 16;
  int m  = bm * 128 + lr;
  int b  = m >> tcshift;
  int tl = m & (Tc - 1);
  const u16* asrc = xb + (size_t)(b * Tv + t0 + tl) * Iv + lk;
  int nrow = bn * 128 + lr;
  const u16* bsrc = wxb + (size_t)nrow * Iv + lk;
  u16* adst = &Al[lr * 40 + lk];
  u16* bdst = &Bl[lr * 40 + lk];

  for (int k0 = 0; k0 < Iv; k0 += 32) {
    __syncthreads();
    *(uint4*)adst       = *(const uint4*)(asrc);
    *(uint4*)(adst + 8) = *(const uint4*)(asrc + 8);
    *(uint4*)bdst       = *(const uint4*)(bsrc);
    *(uint4*)(bdst + 8) = *(const uint4*)(bsrc + 8);
    asrc += 32; bsrc += 32;
    __syncthreads();
#pragma unroll
    for (int kt = 0; kt < 2; ++kt) {
      int ko = kt * 16 + (lane >> 5) * 8;
      bf16x8 a0 = *(const bf16x8*)(&Al[(wm * 64 +      (lane & 31)) * 40 + ko]);
      bf16x8 a1 = *(const bf16x8*)(&Al[(wm * 64 + 32 + (lane & 31)) * 40 + ko]);
      bf16x8 b0 = *(const bf16x8*)(&Bl[(wn * 64 +      (lane & 31)) * 40 + ko]);
      bf16x8 b1 = *(const bf16x8*)(&Bl[(wn * 64 + 32 + (lane & 31)) * 40 + ko]);
      acc[0][0] = mfma32(a0, b0, acc[0][0]);
      acc[0][1] = mfma32(a0, b1, acc[0][1]);
      acc[1][0] = mfma32(a1, b0, acc[1][0]);
      acc[1][1] = mfma32(a1, b1, acc[1][1]);
    }
  }
#pragma unroll
  for (int mt = 0; mt < 2; ++mt) {
#pragma unroll
    for (int ntt = 0; ntt < 2; ++ntt) {
      int nGl = bn * 128 + wn * 64 + ntt * 32 + (lane & 31);
      float bias = bx[nGl] + bh[nGl];
#pragma unroll
      for (int r = 0; r < 16; ++r) {
        int mrow = (r & 3) + 8 * (r >> 2) + 4 * (lane >> 5);
        int mG = bm * 128 + wm * 64 + mt * 32 + mrow;
        int bb = mG >> tcshift;
        int tt = mG & (Tc - 1);
        xg[((size_t)(tt * Bv + bb) << 12) + nGl] = acc[mt][ntt][r] + bias;
      }
    }
  }
}

// ---------------- persistent scan: 64 blocks x 256 thr
// Sync: per-(block,wave) flag array replaces the serialized atomic counter
// barrier. Wave kh consumes kt-slots [16kh,16kh+16) only, so it polls exactly
// the 64 flags of its 16 producer blocks (one wave-wide load per probe).
// Safety:
//  - RAW on hA: wave polls flags[prod*4+w] >= t before reading h_{t-1}.
//  - WAR on hA (h_t overwrites h_{t-2}): stores happen after S1, which requires
//    all 4 local waves passed their polls => all 256 flags >= t => every wave
//    everywhere finished step t-1 (and its reads of h_{t-2}).
//  - red LDS is double-buffered on step parity; the transitive flag chain
//    (producer S1 at t+1 -> its wave bl>>4 polled our flag >= t+1) orders
//    step-t reads before step-t+2 writes of the same parity.
// Flag is published after a vmcnt(0) that covers ONLY the wave's own hA stores;
// out stores + xg prefetch are issued after the flag (off the critical path).
__global__ __launch_bounds__(256, 1) void k_scan(const u16* __restrict__ whf, const float* __restrict__ xg,
                                                 u64* __restrict__ hA, float* __restrict__ cbuf,
                                                 float* __restrict__ out, int* flags, int t0, int Tc) {
  __shared__ float red[2][4][64][36];   // [parity][kh][gate-row][batch] partials, 73728 B
  int tid = threadIdx.x;
  int bl = blockIdx.x;                  // 0..63, owns units u0..u0+15
  int kh = tid >> 6, lane = tid & 63;   // wave = k-quarter
  int eu = tid & 15, eb = tid >> 4;     // epilogue: unit-in-block, batch 0..15 (+16)
  int u0 = bl * 16;

  // preload weights into registers, once: w0/w1 = nt0/nt1 fragments for kt=kh*16+kk
  bf16x8 w0[16], w1[16];
  {
    const u16* wb0 = whf + ((size_t)(bl * 2 + 0) << 15);
    const u16* wb1 = whf + ((size_t)(bl * 2 + 1) << 15);
#pragma unroll
    for (int kk = 0; kk < 16; ++kk) {
      int kt = kh * 16 + kk;
      w0[kk] = *(const bf16x8*)(wb0 + (size_t)((kt << 6) + lane) * 8);
      w1[kk] = *(const bf16x8*)(wb1 + (size_t)((kt << 6) + lane) * 8);
    }
  }

  float c0, c1;
  if (t0 == 0) { c0 = 0.f; c1 = 0.f; }
  else {
    c0 = cbuf[eb * Hv + u0 + eu];
    c1 = cbuf[(eb + 16) * Hv + u0 + eu];
  }

  u16* hA16 = (u16*)hA;
  // this wave's poll slot: lane i covers producer (block 16kh + i/4, wave i%4)
  int* fp = flags + (kh << 6) + lane;

  // xg prefetch for tl=0
  float xgv[4][2];
#pragma unroll
  for (int g = 0; g < 4; ++g)
#pragma unroll
    for (int b2 = 0; b2 < 2; ++b2)
      xgv[g][b2] = xg[((size_t)(0 * Bv + eb + 16 * b2) << 12) + g * Hv + u0 + eu];

  for (int tl = 0; tl < Tc; ++tl) {
    int t = t0 + tl;

    // wait for the 16 producer blocks (all 4 waves each) of this wave's k-slice
    while (__hip_atomic_load(fp, __ATOMIC_RELAXED, __HIP_MEMORY_SCOPE_AGENT) < t) {
      __builtin_amdgcn_s_sleep(0);   // throttle poll storm; ~1cy wake cost
    }
    asm volatile("" ::: "memory");

    const u64* hAr = hA + (size_t)(t & 1) * 8192;  // read buffer (8192 u64 each)

    // hoist all 32 LLC loads so latency is paid once, then run the MFMA chains
    u64 alo[16], ahi[16];
#pragma unroll
    for (int kk = 0; kk < 16; ++kk) {
      size_t fi = (size_t)((((kh << 4) + kk) << 6) + lane) * 2;
      alo[kk] = ld_agent_u64(hAr + fi);
      ahi[kk] = ld_agent_u64(hAr + fi + 1);
    }

    floatx16 acc0, acc1;
#pragma unroll
    for (int r = 0; r < 16; ++r) { acc0[r] = 0.f; acc1[r] = 0.f; }
#pragma unroll
    for (int kk = 0; kk < 16; ++kk) {
      bf16x8 a = mk_frag(alo[kk], ahi[kk]);
      acc0 = mfma32(a, w0[kk], acc0);
      acc1 = mfma32(a, w1[kk], acc1);
    }

    // write k-partials: row = nt*32 + (lane&31); b = (r&3) + 8*(r>>2) + 4*(lane>>5)
    {
      int n = lane & 31;
      int bq = 4 * (lane >> 5);
#pragma unroll
      for (int rq = 0; rq < 4; ++rq) {
        float4 v0 = make_float4(acc0[rq * 4 + 0], acc0[rq * 4 + 1], acc0[rq * 4 + 2], acc0[rq * 4 + 3]);
        float4 v1 = make_float4(acc1[rq * 4 + 0], acc1[rq * 4 + 1], acc1[rq * 4 + 2], acc1[rq * 4 + 3]);
        *(float4*)&red[t & 1][kh][n][8 * rq + bq]      = v0;
        *(float4*)&red[t & 1][kh][32 + n][8 * rq + bq] = v1;
      }
    }

    __syncthreads();   // S1: join waves for the cross-wave reduce

    // epilogue: thread -> (eu, eb) and (eu, eb+16); compute both halves first
    float hv0, hv1;
    {
      float gs[4][2];
#pragma unroll
      for (int g = 0; g < 4; ++g) {
        int r = g * 16 + eu;
#pragma unroll
        for (int b2 = 0; b2 < 2; ++b2) {
          int b = eb + 16 * b2;
          gs[g][b2] = red[t & 1][0][r][b] + red[t & 1][1][r][b] +
                      red[t & 1][2][r][b] + red[t & 1][3][r][b] + xgv[g][b2];
        }
      }
      float i0 = 1.f / (1.f + __expf(-gs[0][0]));
      float f0 = 1.f / (1.f + __expf(-gs[1][0]));
      float g0 = 1.f - 2.f / (__expf(2.f * gs[2][0]) + 1.f);
      float o0 = 1.f / (1.f + __expf(-gs[3][0]));
      c0 = f0 * c0 + i0 * g0;
      hv0 = o0 * (1.f - 2.f / (__expf(2.f * c0) + 1.f));

      float i1 = 1.f / (1.f + __expf(-gs[0][1]));
      float f1 = 1.f / (1.f + __expf(-gs[1][1]));
      float g1 = 1.f - 2.f / (__expf(2.f * gs[2][1]) + 1.f);
      float o1 = 1.f / (1.f + __expf(-gs[3][1]));
      c1 = f1 * c1 + i1 * g1;
      hv1 = o1 * (1.f - 2.f / (__expf(2.f * c1) + 1.f));
    }

    // publish h: only the two hA stores sit before the drain; then the flag.
    u16* hAw16 = hA16 + (size_t)((t + 1) & 1) * 32768;
    st_agent_u16(hAw16 + ((size_t)((bl << 6) + eb +      ((eu >> 3) << 5)) << 3) + (eu & 7), f2bf(hv0));
    st_agent_u16(hAw16 + ((size_t)((bl << 6) + eb + 16 + ((eu >> 3) << 5)) << 3) + (eu & 7), f2bf(hv1));
    asm volatile("s_waitcnt vmcnt(0)" ::: "memory");
    if (lane == 0)
      __hip_atomic_store(flags + (bl << 2) + kh, t + 1, __ATOMIC_RELAXED, __HIP_MEMORY_SCOPE_AGENT);

    // off-critical-path work: out stores (plain, L2-ack) + next xg prefetch
    out[((size_t)(eb * Tv + t) << 10) + u0 + eu] = hv0;
    out[((size_t)((eb + 16) * Tv + t) << 10) + u0 + eu] = hv1;

    {
      int tln = (tl + 1 < Tc) ? tl + 1 : tl;
#pragma unroll
      for (int g = 0; g < 4; ++g)
#pragma unroll
        for (int b2 = 0; b2 < 2; ++b2)
          xgv[g][b2] = xg[((size_t)(tln * Bv + eb + 16 * b2) << 12) + g * Hv + u0 + eu];
    }
  }
  cbuf[eb * Hv + u0 + eu] = c0;
  cbuf[(eb + 16) * Hv + u0 + eu] = c1;
}

extern "C" void kernel_launch(void* const* d_in, const int* in_sizes, int n_in,
                              void* d_out, int out_size, void* d_ws, size_t ws_size,
                              hipStream_t stream) {
  const float* x  = (const float*)d_in[0];
  const float* Wx = (const float*)d_in[1];
  const float* bx = (const float*)d_in[2];
  const float* Wh = (const float*)d_in[3];
  const float* bh = (const float*)d_in[4];
  float* out = (float*)d_out;
  char* ws = (char*)d_ws;

  // ws layout
  int*   flags = (int*)ws;                                 // [0, 4KB): 256 per-(block,wave) flags
  u64*   hA  = (u64*)(ws + 4096);                          // 128 KB (2 x 64KB)
  float* cb  = (float*)(ws + 4096 + (128 << 10));          // 128 KB
  u16*   xb  = (u16*)(ws + 4096 + (256 << 10));            // 16 MB
  u16*   wxb = xb + (size_t)Bv * Tv * Iv;                  // 4 MB
  u16*   whf = wxb + (size_t)NG * Iv;                      // 8 MB
  float* xg  = (float*)(whf + (size_t)64 * 2 * 64 * 64 * 8);

  size_t fixedB = 4096 + (256ull << 10) +
                  ((size_t)Bv * Tv * Iv + (size_t)NG * Iv + (size_t)64 * 2 * 64 * 64 * 8) * 2;
  int tcshift = 9;
  while (tcshift > 2 && fixedB + (((size_t)Bv * NG * 4) << tcshift) > ws_size) --tcshift;
  int Tc = 1 << tcshift;

  k_init<<<132, 256, 0, stream>>>((unsigned int*)ws, (4096 + (128 << 10)) / 4);
  k_f2bf<<<(Bv * Tv * Iv) / 256, 256, 0, stream>>>(x, xb, Bv * Tv * Iv);
  k_f2bf<<<(NG * Iv) / 256, 256, 0, stream>>>(Wx, wxb, NG * Iv);
  k_whf<<<2048, 256, 0, stream>>>(Wh, whf);

  for (int t0 = 0; t0 < Tv; t0 += Tc) {
    k_xg<<<dim3(Tc / 4, 32), 256, 0, stream>>>(xb, wxb, bx, bh, xg, t0, tcshift);
    k_scan<<<64, 256, 0, stream>>>(whf, xg, hA, cb, out, flags, t0, Tc);
  }
}

// Round 3
// 2527.153 us; speedup vs baseline: 1.2040x; 1.2040x over previous
//
#include <hip/hip_runtime.h>
#include <hip/hip_bf16.h>

#define Bv 32
#define Tv 512
#define Iv 512
#define Hv 1024
#define NG 4096  // 4*H

typedef short bf16x8 __attribute__((ext_vector_type(8)));   // 8 bf16 held as i16 (guide §3)
typedef float floatx16 __attribute__((ext_vector_type(16)));
typedef unsigned short u16;
typedef unsigned long long u64;

__device__ __forceinline__ u16 f2bf(float f) {
  __hip_bfloat16 h = __float2bfloat16(f);
  return *reinterpret_cast<u16*>(&h);
}

__device__ __forceinline__ floatx16 mfma32(bf16x8 a, bf16x8 b, floatx16 c) {
  return __builtin_amdgcn_mfma_f32_32x32x16_bf16(a, b, c, 0, 0, 0);
}

// relaxed agent-scope accesses: lower to global_load/store with sc1 (LLC-direct,
// bypass non-coherent per-XCD L2). No cache-maintenance instructions emitted.
__device__ __forceinline__ u64 ld_agent_u64(const u64* p) {
  return __hip_atomic_load(p, __ATOMIC_RELAXED, __HIP_MEMORY_SCOPE_AGENT);
}
__device__ __forceinline__ void st_agent_u16(u16* p, u16 v) {
  __hip_atomic_store(p, v, __ATOMIC_RELAXED, __HIP_MEMORY_SCOPE_AGENT);
}

__device__ __forceinline__ bf16x8 mk_frag(u64 lo, u64 hi) {
  union { u64 q[2]; bf16x8 v; } u;
  u.q[0] = lo; u.q[1] = hi;
  return u.v;
}

// ---------------- init: zero arrival region (4KB) + hA double buffer (128KB)
__global__ void k_init(unsigned int* p, int n) {
  int i = blockIdx.x * blockDim.x + threadIdx.x;
  if (i < n) p[i] = 0u;
}

// ---------------- elementwise fp32 -> bf16
__global__ void k_f2bf(const float* __restrict__ in, u16* __restrict__ out, int n) {
  int i = blockIdx.x * blockDim.x + threadIdx.x;
  if (i < n) out[i] = f2bf(in[i]);
}

// ---------------- gather Wh into B-fragment layout: WhF[bl(64)][nt(2)][kt(64)][lane(64)][8]
__global__ void k_whf(const float* __restrict__ Wh, u16* __restrict__ whf) {
  int tid = blockIdx.x * 256 + threadIdx.x;   // 2048*256 = 524288
  int lane = tid & 63;
  int kt   = (tid >> 6) & 63;
  int nt   = (tid >> 12) & 1;
  int bl   = tid >> 13;
  int r    = nt * 32 + (lane & 31);
  int gate = r >> 4, du = r & 15;
  int row  = gate * Hv + bl * 16 + du;
  int k0   = kt * 16 + (lane >> 5) * 8;
  const float* s = Wh + (size_t)row * Hv + k0;
  u16* d = whf + (size_t)tid * 8;
#pragma unroll
  for (int j = 0; j < 8; ++j) d[j] = f2bf(s[j]);
}

// ---------------- xg GEMM (unchanged)
__global__ __launch_bounds__(256) void k_xg(const u16* __restrict__ xb, const u16* __restrict__ wxb,
                                            const float* __restrict__ bx, const float* __restrict__ bh,
                                            float* __restrict__ xg, int t0, int tcshift) {
  __shared__ u16 Al[128 * 40];
  __shared__ u16 Bl[128 * 40];
  int tid = threadIdx.x;
  int wave = tid >> 6, lane = tid & 63;
  int wm = wave & 1, wn = wave >> 1;
  int bm = blockIdx.x, bn = blockIdx.y;
  int Tc = 1 << tcshift;

  floatx16 acc[2][2];
#pragma unroll
  for (int a = 0; a < 2; ++a)
#pragma unroll
    for (int c = 0; c < 2; ++c)
#pragma unroll
      for (int r = 0; r < 16; ++r) acc[a][c][r] = 0.f;

  int lr = tid >> 1;
  int lk = (tid & 1) * 16;
  int m  = bm * 128 + lr;
  int b  = m >> tcshift;
  int tl = m & (Tc - 1);
  const u16* asrc = xb + (size_t)(b * Tv + t0 + tl) * Iv + lk;
  int nrow = bn * 128 + lr;
  const u16* bsrc = wxb + (size_t)nrow * Iv + lk;
  u16* adst = &Al[lr * 40 + lk];
  u16* bdst = &Bl[lr * 40 + lk];

  for (int k0 = 0; k0 < Iv; k0 += 32) {
    __syncthreads();
    *(uint4*)adst       = *(const uint4*)(asrc);
    *(uint4*)(adst + 8) = *(const uint4*)(asrc + 8);
    *(uint4*)bdst       = *(const uint4*)(bsrc);
    *(uint4*)(bdst + 8) = *(const uint4*)(bsrc + 8);
    asrc += 32; bsrc += 32;
    __syncthreads();
#pragma unroll
    for (int kt = 0; kt < 2; ++kt) {
      int ko = kt * 16 + (lane >> 5) * 8;
      bf16x8 a0 = *(const bf16x8*)(&Al[(wm * 64 +      (lane & 31)) * 40 + ko]);
      bf16x8 a1 = *(const bf16x8*)(&Al[(wm * 64 + 32 + (lane & 31)) * 40 + ko]);
      bf16x8 b0 = *(const bf16x8*)(&Bl[(wn * 64 +      (lane & 31)) * 40 + ko]);
      bf16x8 b1 = *(const bf16x8*)(&Bl[(wn * 64 + 32 + (lane & 31)) * 40 + ko]);
      acc[0][0] = mfma32(a0, b0, acc[0][0]);
      acc[0][1] = mfma32(a0, b1, acc[0][1]);
      acc[1][0] = mfma32(a1, b0, acc[1][0]);
      acc[1][1] = mfma32(a1, b1, acc[1][1]);
    }
  }
#pragma unroll
  for (int mt = 0; mt < 2; ++mt) {
#pragma unroll
    for (int ntt = 0; ntt < 2; ++ntt) {
      int nGl = bn * 128 + wn * 64 + ntt * 32 + (lane & 31);
      float bias = bx[nGl] + bh[nGl];
#pragma unroll
      for (int r = 0; r < 16; ++r) {
        int mrow = (r & 3) + 8 * (r >> 2) + 4 * (lane >> 5);
        int mG = bm * 128 + wm * 64 + mt * 32 + mrow;
        int bb = mG >> tcshift;
        int tt = mG & (Tc - 1);
        xg[((size_t)(tt * Bv + bb) << 12) + nGl] = acc[mt][ntt][r] + bias;
      }
    }
  }
}

// ---------------- persistent scan: 64 blocks x 256 thr
// Barrier = 64 independent arrival stores (spread 64B apart; NO atomic RMW) +
// one poller wave per block gathering all 64 arrivals, then __syncthreads
// release. Rationale: round-0's atomicAdd chain = 64 same-line RMWs serialized
// under read pressure (~3us/step); round-2's per-wave flags quadrupled publish
// and poll traffic with zero skew absorption. This keeps round-0's proven
// 3-barrier structure and only de-serializes the arrival.
// Safety (identical ordering to round-0):
//  - RAW on hA: step t+1 reads gated by poll(all arrivals >= t+1) at end of t.
//  - WAR on hA: step t+1 stores happen after the same release, which implies
//    every block finished its step-t reads of the buffer being overwritten.
//  - red LDS: reads (epilogue, after S1) precede S2; next writes after S3.
__global__ __launch_bounds__(256, 1) void k_scan(const u16* __restrict__ whf, const float* __restrict__ xg,
                                                 u64* __restrict__ hA, float* __restrict__ cbuf,
                                                 float* __restrict__ out, int* arrivals, int t0, int Tc) {
  __shared__ float red[4][64][36];   // [kh][gate-row][batch] partials, 36864 B
  int tid = threadIdx.x;
  int bl = blockIdx.x;                  // 0..63, owns units u0..u0+15
  int kh = tid >> 6, lane = tid & 63;   // wave = k-quarter
  int eu = tid & 15, eb = tid >> 4;     // epilogue: unit-in-block, batch 0..15 (+16)
  int u0 = bl * 16;

  // preload weights into registers, once: w0/w1 = nt0/nt1 fragments for kt=kh*16+kk
  bf16x8 w0[16], w1[16];
  {
    const u16* wb0 = whf + ((size_t)(bl * 2 + 0) << 15);
    const u16* wb1 = whf + ((size_t)(bl * 2 + 1) << 15);
#pragma unroll
    for (int kk = 0; kk < 16; ++kk) {
      int kt = kh * 16 + kk;
      w0[kk] = *(const bf16x8*)(wb0 + (size_t)((kt << 6) + lane) * 8);
      w1[kk] = *(const bf16x8*)(wb1 + (size_t)((kt << 6) + lane) * 8);
    }
  }

  float c0, c1;
  if (t0 == 0) { c0 = 0.f; c1 = 0.f; }
  else {
    c0 = cbuf[eb * Hv + u0 + eu];
    c1 = cbuf[(eb + 16) * Hv + u0 + eu];
  }

  u16* hA16 = (u16*)hA;

  // xg prefetch for tl=0
  float xgv[4][2];
#pragma unroll
  for (int g = 0; g < 4; ++g)
#pragma unroll
    for (int b2 = 0; b2 < 2; ++b2)
      xgv[g][b2] = xg[((size_t)(0 * Bv + eb + 16 * b2) << 12) + g * Hv + u0 + eu];

  for (int tl = 0; tl < Tc; ++tl) {
    int t = t0 + tl;
    const u64* hAr = hA + (size_t)(t & 1) * 8192;  // read buffer (8192 u64 each)

    // hoist all 32 LLC loads so latency is paid once, then run the MFMA chains
    u64 alo[16], ahi[16];
#pragma unroll
    for (int kk = 0; kk < 16; ++kk) {
      size_t fi = (size_t)((((kh << 4) + kk) << 6) + lane) * 2;
      alo[kk] = ld_agent_u64(hAr + fi);
      ahi[kk] = ld_agent_u64(hAr + fi + 1);
    }

    floatx16 acc0, acc1;
#pragma unroll
    for (int r = 0; r < 16; ++r) { acc0[r] = 0.f; acc1[r] = 0.f; }
#pragma unroll
    for (int kk = 0; kk < 16; ++kk) {
      bf16x8 a = mk_frag(alo[kk], ahi[kk]);
      acc0 = mfma32(a, w0[kk], acc0);
      acc1 = mfma32(a, w1[kk], acc1);
    }

    // write k-partials: row = nt*32 + (lane&31); b = (r&3) + 8*(r>>2) + 4*(lane>>5)
    {
      int n = lane & 31;
      int bq = 4 * (lane >> 5);
#pragma unroll
      for (int rq = 0; rq < 4; ++rq) {
        float4 v0 = make_float4(acc0[rq * 4 + 0], acc0[rq * 4 + 1], acc0[rq * 4 + 2], acc0[rq * 4 + 3]);
        float4 v1 = make_float4(acc1[rq * 4 + 0], acc1[rq * 4 + 1], acc1[rq * 4 + 2], acc1[rq * 4 + 3]);
        *(float4*)&red[kh][n][8 * rq + bq]      = v0;
        *(float4*)&red[kh][32 + n][8 * rq + bq] = v1;
      }
    }

    __syncthreads();   // S1: join waves for the cross-wave reduce

    // epilogue: thread -> (eu, eb) and (eu, eb+16)
    float hv0, hv1;
    {
      float gs[4][2];
#pragma unroll
      for (int g = 0; g < 4; ++g) {
        int r = g * 16 + eu;
#pragma unroll
        for (int b2 = 0; b2 < 2; ++b2) {
          int b = eb + 16 * b2;
          gs[g][b2] = red[0][r][b] + red[1][r][b] + red[2][r][b] + red[3][r][b] + xgv[g][b2];
        }
      }
      float i0 = 1.f / (1.f + __expf(-gs[0][0]));
      float f0 = 1.f / (1.f + __expf(-gs[1][0]));
      float g0 = 1.f - 2.f / (__expf(2.f * gs[2][0]) + 1.f);
      float o0 = 1.f / (1.f + __expf(-gs[3][0]));
      c0 = f0 * c0 + i0 * g0;
      hv0 = o0 * (1.f - 2.f / (__expf(2.f * c0) + 1.f));

      float i1 = 1.f / (1.f + __expf(-gs[0][1]));
      float f1 = 1.f / (1.f + __expf(-gs[1][1]));
      float g1 = 1.f - 2.f / (__expf(2.f * gs[2][1]) + 1.f);
      float o1 = 1.f / (1.f + __expf(-gs[3][1]));
      c1 = f1 * c1 + i1 * g1;
      hv1 = o1 * (1.f - 2.f / (__expf(2.f * c1) + 1.f));
    }

    // publish h: only the two hA stores sit before the drain
    u16* hAw16 = hA16 + (size_t)((t + 1) & 1) * 32768;
    st_agent_u16(hAw16 + ((size_t)((bl << 6) + eb +      ((eu >> 3) << 5)) << 3) + (eu & 7), f2bf(hv0));
    st_agent_u16(hAw16 + ((size_t)((bl << 6) + eb + 16 + ((eu >> 3) << 5)) << 3) + (eu & 7), f2bf(hv1));
    asm volatile("s_waitcnt vmcnt(0)" ::: "memory");
    __syncthreads();   // S2: whole block's hA stores are drained

    // arrival: plain store, own 64B slot (2 blocks/cacheline) — no RMW chain
    if (tid == 0)
      __hip_atomic_store(arrivals + bl * 16, t + 1, __ATOMIC_RELAXED, __HIP_MEMORY_SCOPE_AGENT);

    // off-critical-path work: out stores + next xg prefetch (hide under poll)
    out[((size_t)(eb * Tv + t) << 10) + u0 + eu] = hv0;
    out[((size_t)((eb + 16) * Tv + t) << 10) + u0 + eu] = hv1;
    {
      int tln = (tl + 1 < Tc) ? tl + 1 : tl;
#pragma unroll
      for (int g = 0; g < 4; ++g)
#pragma unroll
        for (int b2 = 0; b2 < 2; ++b2)
          xgv[g][b2] = xg[((size_t)(tln * Bv + eb + 16 * b2) << 12) + g * Hv + u0 + eu];
    }

    // release: wave 0 gathers all 64 arrivals (one line-parallel load per round)
    if (tl + 1 < Tc) {
      if (tid < 64) {
        const int* ap = arrivals + tid * 16;
        while (__hip_atomic_load(ap, __ATOMIC_RELAXED, __HIP_MEMORY_SCOPE_AGENT) < t + 1) { }
      }
      __syncthreads();   // S3: release whole block into step t+1
    }
  }
  cbuf[eb * Hv + u0 + eu] = c0;
  cbuf[(eb + 16) * Hv + u0 + eu] = c1;
}

extern "C" void kernel_launch(void* const* d_in, const int* in_sizes, int n_in,
                              void* d_out, int out_size, void* d_ws, size_t ws_size,
                              hipStream_t stream) {
  const float* x  = (const float*)d_in[0];
  const float* Wx = (const float*)d_in[1];
  const float* bx = (const float*)d_in[2];
  const float* Wh = (const float*)d_in[3];
  const float* bh = (const float*)d_in[4];
  float* out = (float*)d_out;
  char* ws = (char*)d_ws;

  // ws layout
  int*   arrivals = (int*)ws;                              // [0, 4KB): 64 arrivals, 64B apart
  u64*   hA  = (u64*)(ws + 4096);                          // 128 KB (2 x 64KB)
  float* cb  = (float*)(ws + 4096 + (128 << 10));          // 128 KB
  u16*   xb  = (u16*)(ws + 4096 + (256 << 10));            // 16 MB
  u16*   wxb = xb + (size_t)Bv * Tv * Iv;                  // 4 MB
  u16*   whf = wxb + (size_t)NG * Iv;                      // 8 MB
  float* xg  = (float*)(whf + (size_t)64 * 2 * 64 * 64 * 8);

  size_t fixedB = 4096 + (256ull << 10) +
                  ((size_t)Bv * Tv * Iv + (size_t)NG * Iv + (size_t)64 * 2 * 64 * 64 * 8) * 2;
  int tcshift = 9;
  while (tcshift > 2 && fixedB + (((size_t)Bv * NG * 4) << tcshift) > ws_size) --tcshift;
  int Tc = 1 << tcshift;

  k_init<<<132, 256, 0, stream>>>((unsigned int*)ws, (4096 + (128 << 10)) / 4);
  k_f2bf<<<(Bv * Tv * Iv) / 256, 256, 0, stream>>>(x, xb, Bv * Tv * Iv);
  k_f2bf<<<(NG * Iv) / 256, 256, 0, stream>>>(Wx, wxb, NG * Iv);
  k_whf<<<2048, 256, 0, stream>>>(Wh, whf);

  for (int t0 = 0; t0 < Tv; t0 += Tc) {
    k_xg<<<dim3(Tc / 4, 32), 256, 0, stream>>>(xb, wxb, bx, bh, xg, t0, tcshift);
    k_scan<<<64, 256, 0, stream>>>(whf, xg, hA, cb, out, arrivals, t0, Tc);
  }
}

// Round 4
// 2390.882 us; speedup vs baseline: 1.2726x; 1.0570x over previous
//
#include <hip/hip_runtime.h>
#include <hip/hip_bf16.h>

#define Bv 32
#define Tv 512
#define Iv 512
#define Hv 1024
#define NG 4096  // 4*H

typedef short bf16x8 __attribute__((ext_vector_type(8)));   // 8 bf16 held as i16 (guide §3)
typedef float floatx16 __attribute__((ext_vector_type(16)));
typedef unsigned short u16;
typedef unsigned long long u64;

__device__ __forceinline__ u16 f2bf(float f) {
  __hip_bfloat16 h = __float2bfloat16(f);
  return *reinterpret_cast<u16*>(&h);
}

__device__ __forceinline__ floatx16 mfma32(bf16x8 a, bf16x8 b, floatx16 c) {
  return __builtin_amdgcn_mfma_f32_32x32x16_bf16(a, b, c, 0, 0, 0);
}

// relaxed agent-scope accesses: lower to global_load/store with sc1 (LLC-direct,
// bypass non-coherent per-XCD L2). No cache-maintenance instructions emitted.
__device__ __forceinline__ u64 ld_agent_u64(const u64* p) {
  return __hip_atomic_load(p, __ATOMIC_RELAXED, __HIP_MEMORY_SCOPE_AGENT);
}
__device__ __forceinline__ void st_agent_u16(u16* p, u16 v) {
  __hip_atomic_store(p, v, __ATOMIC_RELAXED, __HIP_MEMORY_SCOPE_AGENT);
}

__device__ __forceinline__ bf16x8 mk_frag(u64 lo, u64 hi) {
  union { u64 q[2]; bf16x8 v; } u;
  u.q[0] = lo; u.q[1] = hi;
  return u.v;
}

// ---------------- init: zero arrival region (4KB) + hA double buffer (128KB)
__global__ void k_init(unsigned int* p, int n) {
  int i = blockIdx.x * blockDim.x + threadIdx.x;
  if (i < n) p[i] = 0u;
}

// ---------------- elementwise fp32 -> bf16
__global__ void k_f2bf(const float* __restrict__ in, u16* __restrict__ out, int n) {
  int i = blockIdx.x * blockDim.x + threadIdx.x;
  if (i < n) out[i] = f2bf(in[i]);
}

// ---------------- gather Wh into B-fragment layout: WhF[bl(64)][nt(2)][kt(64)][lane(64)][8]
__global__ void k_whf(const float* __restrict__ Wh, u16* __restrict__ whf) {
  int tid = blockIdx.x * 256 + threadIdx.x;   // 2048*256 = 524288
  int lane = tid & 63;
  int kt   = (tid >> 6) & 63;
  int nt   = (tid >> 12) & 1;
  int bl   = tid >> 13;
  int r    = nt * 32 + (lane & 31);
  int gate = r >> 4, du = r & 15;
  int row  = gate * Hv + bl * 16 + du;
  int k0   = kt * 16 + (lane >> 5) * 8;
  const float* s = Wh + (size_t)row * Hv + k0;
  u16* d = whf + (size_t)tid * 8;
#pragma unroll
  for (int j = 0; j < 8; ++j) d[j] = f2bf(s[j]);
}

// ---------------- xg GEMM (unchanged)
__global__ __launch_bounds__(256) void k_xg(const u16* __restrict__ xb, const u16* __restrict__ wxb,
                                            const float* __restrict__ bx, const float* __restrict__ bh,
                                            float* __restrict__ xg, int t0, int tcshift) {
  __shared__ u16 Al[128 * 40];
  __shared__ u16 Bl[128 * 40];
  int tid = threadIdx.x;
  int wave = tid >> 6, lane = tid & 63;
  int wm = wave & 1, wn = wave >> 1;
  int bm = blockIdx.x, bn = blockIdx.y;
  int Tc = 1 << tcshift;

  floatx16 acc[2][2];
#pragma unroll
  for (int a = 0; a < 2; ++a)
#pragma unroll
    for (int c = 0; c < 2; ++c)
#pragma unroll
      for (int r = 0; r < 16; ++r) acc[a][c][r] = 0.f;

  int lr = tid >> 1;
  int lk = (tid & 1) * 16;
  int m  = bm * 128 + lr;
  int b  = m >> tcshift;
  int tl = m & (Tc - 1);
  const u16* asrc = xb + (size_t)(b * Tv + t0 + tl) * Iv + lk;
  int nrow = bn * 128 + lr;
  const u16* bsrc = wxb + (size_t)nrow * Iv + lk;
  u16* adst = &Al[lr * 40 + lk];
  u16* bdst = &Bl[lr * 40 + lk];

  for (int k0 = 0; k0 < Iv; k0 += 32) {
    __syncthreads();
    *(uint4*)adst       = *(const uint4*)(asrc);
    *(uint4*)(adst + 8) = *(const uint4*)(asrc + 8);
    *(uint4*)bdst       = *(const uint4*)(bsrc);
    *(uint4*)(bdst + 8) = *(const uint4*)(bsrc + 8);
    asrc += 32; bsrc += 32;
    __syncthreads();
#pragma unroll
    for (int kt = 0; kt < 2; ++kt) {
      int ko = kt * 16 + (lane >> 5) * 8;
      bf16x8 a0 = *(const bf16x8*)(&Al[(wm * 64 +      (lane & 31)) * 40 + ko]);
      bf16x8 a1 = *(const bf16x8*)(&Al[(wm * 64 + 32 + (lane & 31)) * 40 + ko]);
      bf16x8 b0 = *(const bf16x8*)(&Bl[(wn * 64 +      (lane & 31)) * 40 + ko]);
      bf16x8 b1 = *(const bf16x8*)(&Bl[(wn * 64 + 32 + (lane & 31)) * 40 + ko]);
      acc[0][0] = mfma32(a0, b0, acc[0][0]);
      acc[0][1] = mfma32(a0, b1, acc[0][1]);
      acc[1][0] = mfma32(a1, b0, acc[1][0]);
      acc[1][1] = mfma32(a1, b1, acc[1][1]);
    }
  }
#pragma unroll
  for (int mt = 0; mt < 2; ++mt) {
#pragma unroll
    for (int ntt = 0; ntt < 2; ++ntt) {
      int nGl = bn * 128 + wn * 64 + ntt * 32 + (lane & 31);
      float bias = bx[nGl] + bh[nGl];
#pragma unroll
      for (int r = 0; r < 16; ++r) {
        int mrow = (r & 3) + 8 * (r >> 2) + 4 * (lane >> 5);
        int mG = bm * 128 + wm * 64 + mt * 32 + mrow;
        int bb = mG >> tcshift;
        int tt = mG & (Tc - 1);
        xg[((size_t)(tt * Bv + bb) << 12) + nGl] = acc[mt][ntt][r] + bias;
      }
    }
  }
}

// ---------------- persistent scan: 64 blocks x 256 thr
// Sync design (round 4):
//  - publish: per BLOCK, one tid0 store to arrivals[bl*16] after the whole
//    block's hA stores are drained (vmcnt(0) per wave + S2). Cheap, proven.
//  - release: per WAVE. Wave kh consumes kt-slots [16kh,16kh+16), produced by
//    exactly blocks 16kh..16kh+15 (kt slot index == producer block id). It
//    polls those 16 flags (4 lanes/flag, broadcast) and proceeds straight
//    into its hA loads. No global release barrier, no S3.
//  - poll hygiene: xg prefetch issues at the TOP of the step (completes under
//    MFMA/epilogue); out values stash in LDS and flush once per 16 steps after
//    publish. So a probe's implicit vmcnt(0) waits on (almost) nothing.
// Safety:
//  - RAW on hA: wave's poll (its 16 producers >= t) covers every kt it reads.
//  - WAR on hA: block stores h_{t+1} after S1(t), which needs all 4 waves'
//    polls => all 64 producers published t => everyone finished step-(t-1)
//    reads of the parity buffer being overwritten.
//  - red LDS double-buffered on parity; distance-2 reuse ordered by the
//    transitive publish chain (publish at t+1 requires S2(t) after all
//    epilogue reads of step t).
__global__ __launch_bounds__(256, 1) void k_scan(const u16* __restrict__ whf, const float* __restrict__ xg,
                                                 u64* __restrict__ hA, float* __restrict__ cbuf,
                                                 float* __restrict__ out, int* arrivals, int t0, int Tc) {
  __shared__ float red[2][4][64][36];      // [parity][kh][gate-row][batch], 73728 B
  __shared__ float obuf[16][2][16][16];    // [ts][b2][eb][eu] out stash, 32768 B
  int tid = threadIdx.x;
  int bl = blockIdx.x;                  // 0..63, owns units u0..u0+15
  int kh = tid >> 6, lane = tid & 63;   // wave = k-quarter
  int eu = tid & 15, eb = tid >> 4;     // epilogue: unit-in-block, batch 0..15 (+16)
  int u0 = bl * 16;

  // preload weights into registers, once: w0/w1 = nt0/nt1 fragments for kt=kh*16+kk
  bf16x8 w0[16], w1[16];
  {
    const u16* wb0 = whf + ((size_t)(bl * 2 + 0) << 15);
    const u16* wb1 = whf + ((size_t)(bl * 2 + 1) << 15);
#pragma unroll
    for (int kk = 0; kk < 16; ++kk) {
      int kt = kh * 16 + kk;
      w0[kk] = *(const bf16x8*)(wb0 + (size_t)((kt << 6) + lane) * 8);
      w1[kk] = *(const bf16x8*)(wb1 + (size_t)((kt << 6) + lane) * 8);
    }
  }

  float c0, c1;
  if (t0 == 0) { c0 = 0.f; c1 = 0.f; }
  else {
    c0 = cbuf[eb * Hv + u0 + eu];
    c1 = cbuf[(eb + 16) * Hv + u0 + eu];
  }

  u16* hA16 = (u16*)hA;
  // wave's poll slot: 4 lanes share each of the 16 producer flags
  const int* fp = arrivals + ((kh << 4) + (lane & 15)) * 16;

  // xg prefetch for tl=0
  float xgv[4][2];
#pragma unroll
  for (int g = 0; g < 4; ++g)
#pragma unroll
    for (int b2 = 0; b2 < 2; ++b2)
      xgv[g][b2] = xg[((size_t)(0 * Bv + eb + 16 * b2) << 12) + g * Hv + u0 + eu];

  for (int tl = 0; tl < Tc; ++tl) {
    int t = t0 + tl;

    // per-wave release: my 16 producers (all their waves drained before publish)
    while (__hip_atomic_load(fp, __ATOMIC_RELAXED, __HIP_MEMORY_SCOPE_AGENT) < t) { }
    asm volatile("" ::: "memory");

    const u64* hAr = hA + (size_t)(t & 1) * 8192;  // read buffer (8192 u64 each)

    // hoist all 32 LLC loads; latency paid once
    u64 alo[16], ahi[16];
#pragma unroll
    for (int kk = 0; kk < 16; ++kk) {
      size_t fi = (size_t)((((kh << 4) + kk) << 6) + lane) * 2;
      alo[kk] = ld_agent_u64(hAr + fi);
      ahi[kk] = ld_agent_u64(hAr + fi + 1);
    }

    // xg prefetch for NEXT step, issued early: completes under MFMA+epilogue,
    // so later poll probes' vmcnt(0) never wait on it.
    float xgn[4][2];
    {
      int tln = (tl + 1 < Tc) ? tl + 1 : tl;
#pragma unroll
      for (int g = 0; g < 4; ++g)
#pragma unroll
        for (int b2 = 0; b2 < 2; ++b2)
          xgn[g][b2] = xg[((size_t)(tln * Bv + eb + 16 * b2) << 12) + g * Hv + u0 + eu];
    }

    floatx16 acc0, acc1;
#pragma unroll
    for (int r = 0; r < 16; ++r) { acc0[r] = 0.f; acc1[r] = 0.f; }
#pragma unroll
    for (int kk = 0; kk < 16; ++kk) {
      bf16x8 a = mk_frag(alo[kk], ahi[kk]);
      acc0 = mfma32(a, w0[kk], acc0);
      acc1 = mfma32(a, w1[kk], acc1);
    }

    // write k-partials: row = nt*32 + (lane&31); b = (r&3) + 8*(r>>2) + 4*(lane>>5)
    {
      int n = lane & 31;
      int bq = 4 * (lane >> 5);
#pragma unroll
      for (int rq = 0; rq < 4; ++rq) {
        float4 v0 = make_float4(acc0[rq * 4 + 0], acc0[rq * 4 + 1], acc0[rq * 4 + 2], acc0[rq * 4 + 3]);
        float4 v1 = make_float4(acc1[rq * 4 + 0], acc1[rq * 4 + 1], acc1[rq * 4 + 2], acc1[rq * 4 + 3]);
        *(float4*)&red[t & 1][kh][n][8 * rq + bq]      = v0;
        *(float4*)&red[t & 1][kh][32 + n][8 * rq + bq] = v1;
      }
    }

    __syncthreads();   // S1: join waves for the cross-wave reduce

    // epilogue: thread -> (eu, eb) and (eu, eb+16)
    float hv0, hv1;
    {
      float gs[4][2];
#pragma unroll
      for (int g = 0; g < 4; ++g) {
        int r = g * 16 + eu;
#pragma unroll
        for (int b2 = 0; b2 < 2; ++b2) {
          int b = eb + 16 * b2;
          gs[g][b2] = red[t & 1][0][r][b] + red[t & 1][1][r][b] +
                      red[t & 1][2][r][b] + red[t & 1][3][r][b] + xgv[g][b2];
        }
      }
      float i0 = 1.f / (1.f + __expf(-gs[0][0]));
      float f0 = 1.f / (1.f + __expf(-gs[1][0]));
      float g0 = 1.f - 2.f / (__expf(2.f * gs[2][0]) + 1.f);
      float o0 = 1.f / (1.f + __expf(-gs[3][0]));
      c0 = f0 * c0 + i0 * g0;
      hv0 = o0 * (1.f - 2.f / (__expf(2.f * c0) + 1.f));

      float i1 = 1.f / (1.f + __expf(-gs[0][1]));
      float f1 = 1.f / (1.f + __expf(-gs[1][1]));
      float g1 = 1.f - 2.f / (__expf(2.f * gs[2][1]) + 1.f);
      float o1 = 1.f / (1.f + __expf(-gs[3][1]));
      c1 = f1 * c1 + i1 * g1;
      hv1 = o1 * (1.f - 2.f / (__expf(2.f * c1) + 1.f));
    }

    // stash out values in LDS (flushed every 16 steps, off the poll path)
    {
      int ts = tl & 15;
      obuf[ts][0][eb][eu] = hv0;
      obuf[ts][1][eb][eu] = hv1;
    }

    // publish h: only the two hA stores sit before the drain
    u16* hAw16 = hA16 + (size_t)((t + 1) & 1) * 32768;
    st_agent_u16(hAw16 + ((size_t)((bl << 6) + eb +      ((eu >> 3) << 5)) << 3) + (eu & 7), f2bf(hv0));
    st_agent_u16(hAw16 + ((size_t)((bl << 6) + eb + 16 + ((eu >> 3) << 5)) << 3) + (eu & 7), f2bf(hv1));
    asm volatile("s_waitcnt vmcnt(0)" ::: "memory");
    __syncthreads();   // S2: whole block's hA stores drained

    // arrival: plain store, own 64B slot — no RMW chain
    if (tid == 0)
      __hip_atomic_store(arrivals + bl * 16, t + 1, __ATOMIC_RELAXED, __HIP_MEMORY_SCOPE_AGENT);

    // out flush once per 16 steps (burst overlaps the next poll window)
    if ((tl & 15) == 15 || tl == Tc - 1) {
      int ns = (tl & 15) + 1;
      int tb = t - (tl & 15);
      for (int ts = 0; ts < ns; ++ts) {
        out[((size_t)(eb * Tv + tb + ts) << 10) + u0 + eu]        = obuf[ts][0][eb][eu];
        out[((size_t)((eb + 16) * Tv + tb + ts) << 10) + u0 + eu] = obuf[ts][1][eb][eu];
      }
    }

#pragma unroll
    for (int g = 0; g < 4; ++g)
#pragma unroll
      for (int b2 = 0; b2 < 2; ++b2) xgv[g][b2] = xgn[g][b2];
  }
  cbuf[eb * Hv + u0 + eu] = c0;
  cbuf[(eb + 16) * Hv + u0 + eu] = c1;
}

extern "C" void kernel_launch(void* const* d_in, const int* in_sizes, int n_in,
                              void* d_out, int out_size, void* d_ws, size_t ws_size,
                              hipStream_t stream) {
  const float* x  = (const float*)d_in[0];
  const float* Wx = (const float*)d_in[1];
  const float* bx = (const float*)d_in[2];
  const float* Wh = (const float*)d_in[3];
  const float* bh = (const float*)d_in[4];
  float* out = (float*)d_out;
  char* ws = (char*)d_ws;

  // ws layout
  int*   arrivals = (int*)ws;                              // [0, 4KB): 64 arrivals, 64B apart
  u64*   hA  = (u64*)(ws + 4096);                          // 128 KB (2 x 64KB)
  float* cb  = (float*)(ws + 4096 + (128 << 10));          // 128 KB
  u16*   xb  = (u16*)(ws + 4096 + (256 << 10));            // 16 MB
  u16*   wxb = xb + (size_t)Bv * Tv * Iv;                  // 4 MB
  u16*   whf = wxb + (size_t)NG * Iv;                      // 8 MB
  float* xg  = (float*)(whf + (size_t)64 * 2 * 64 * 64 * 8);

  size_t fixedB = 4096 + (256ull << 10) +
                  ((size_t)Bv * Tv * Iv + (size_t)NG * Iv + (size_t)64 * 2 * 64 * 64 * 8) * 2;
  int tcshift = 9;
  while (tcshift > 2 && fixedB + (((size_t)Bv * NG * 4) << tcshift) > ws_size) --tcshift;
  int Tc = 1 << tcshift;

  k_init<<<132, 256, 0, stream>>>((unsigned int*)ws, (4096 + (128 << 10)) / 4);
  k_f2bf<<<(Bv * Tv * Iv) / 256, 256, 0, stream>>>(x, xb, Bv * Tv * Iv);
  k_f2bf<<<(NG * Iv) / 256, 256, 0, stream>>>(Wx, wxb, NG * Iv);
  k_whf<<<2048, 256, 0, stream>>>(Wh, whf);

  for (int t0 = 0; t0 < Tv; t0 += Tc) {
    k_xg<<<dim3(Tc / 4, 32), 256, 0, stream>>>(xb, wxb, bx, bh, xg, t0, tcshift);
    k_scan<<<64, 256, 0, stream>>>(whf, xg, hA, cb, out, arrivals, t0, Tc);
  }
}